// Round 1
// 451.237 us; speedup vs baseline: 1.0096x; 1.0096x over previous
//
#include <hip/hip_runtime.h>
#include <cstddef>

#define THREADS 256
#define DDIM 2048
#define NBINS 2048

typedef float f4 __attribute__((ext_vector_type(4)));

// One block per row; 256 threads x 8 f32 in registers. x read once (NT), out
// written once (NT). Exact k-th largest |x_norm| via MSB-first radix select
// (11/11/9-bit digits over bits [30:0]).
//
// v2 changes vs the 455us baseline:
//  * sigma-based prefilter: only elements >= pivot (Gaussian-quantile estimate
//    from sum(x^2), sum((x*w)^2)) enter the round-0 histogram (~400 vs 2048
//    LDS atomics/row). Exact fallback: if the histogram holds < k candidates
//    (detected for free by tid 0 during the scan), round 0 reruns with pivot=0.
//    Candidates are precisely the top-C elements, so the k-th among candidates
//    is the global k-th.
//  * early exit: if the target's within-bin rank is 1 (or == bin count), the
//    threshold is the max (min) over elements matching the prefix -> one LDS
//    atomicMax/Min + 1 barrier replaces a whole remaining round. Round 2 runs
//    in <5% of rows on this data.
__global__ __launch_bounds__(THREADS) void sparse_topk_rmsnorm_kernel(
    const float* __restrict__ x,
    const float* __restrict__ weight,
    const float* __restrict__ gamma,
    const int* __restrict__ kp,
    float* __restrict__ out)
{
    const int tid  = threadIdx.x;
    const int lane = tid & 63;
    const int wid  = tid >> 6;
    const long row = blockIdx.x;

    __shared__ __align__(16) unsigned hist[NBINS];
    __shared__ float    wsumf[4];
    __shared__ float    wsumw[4];
    __shared__ unsigned wtot[4];
    __shared__ unsigned s_prefix;
    __shared__ unsigned s_kk;
    __shared__ unsigned s_cnt;
    __shared__ unsigned s_thr;

    const f4*     x4 = (const f4*)(x + row * (long)DDIM);
    const float4* w4 = (const float4*)weight;
    const float4* g4 = (const float4*)gamma;

    // coalesced, stream-once -> nontemporal
    f4 a = __builtin_nontemporal_load(x4 + tid);
    f4 b = __builtin_nontemporal_load(x4 + tid + 256);
    float4 wa = w4[tid];
    float4 wb = w4[tid + 256];
    float4 ga = g4[tid];          // issued early; consumed only in epilogue
    float4 gb = g4[tid + 256];

    // clear histogram (thread owns bins [8t, 8t+8))
    const uint4 zero4 = make_uint4(0u, 0u, 0u, 0u);
    uint4* h4 = (uint4*)hist;
    h4[2*tid]     = zero4;
    h4[2*tid + 1] = zero4;

    // ---- sum(x^2) for rms; sum((x*w)^2) for the pivot sigma ----
    float xw[8];
    xw[0]=a.x*wa.x; xw[1]=a.y*wa.y; xw[2]=a.z*wa.z; xw[3]=a.w*wa.w;
    xw[4]=b.x*wb.x; xw[5]=b.y*wb.y; xw[6]=b.z*wb.z; xw[7]=b.w*wb.w;
    float ss = a.x*a.x + a.y*a.y + a.z*a.z + a.w*a.w
             + b.x*b.x + b.y*b.y + b.z*b.z + b.w*b.w;
    float ssw = xw[0]*xw[0]+xw[1]*xw[1]+xw[2]*xw[2]+xw[3]*xw[3]
              + xw[4]*xw[4]+xw[5]*xw[5]+xw[6]*xw[6]+xw[7]*xw[7];
    #pragma unroll
    for (int off = 32; off > 0; off >>= 1) {
        ss  += __shfl_down(ss,  off, 64);
        ssw += __shfl_down(ssw, off, 64);
    }
    if (lane == 0) { wsumf[wid] = ss; wsumw[wid] = ssw; }
    __syncthreads();                       // B0: sums visible + hist cleared
    const float total = wsumf[0] + wsumf[1] + wsumf[2] + wsumf[3];
    const float totw  = wsumw[0] + wsumw[1] + wsumw[2] + wsumw[3];
    const float rms   = rsqrtf(total * (1.0f / (float)DDIM) + 1e-6f);
    const float sigma = rms * sqrtf(fmaxf(totw, 0.0f) * (1.0f / (float)DDIM));

    // ---- x_norm in reference association order (x*rms)*w (bit-exact) ----
    float nx[8];
    unsigned mb[8];
    nx[0] = a.x * rms * wa.x;  nx[1] = a.y * rms * wa.y;
    nx[2] = a.z * rms * wa.z;  nx[3] = a.w * rms * wa.w;
    nx[4] = b.x * rms * wb.x;  nx[5] = b.y * rms * wb.y;
    nx[6] = b.z * rms * wb.z;  nx[7] = b.w * rms * wb.w;
    #pragma unroll
    for (int i = 0; i < 8; ++i)
        mb[i] = __float_as_uint(fabsf(nx[i]));

    int k0 = kp[0];
    if (k0 < 1)    k0 = 1;
    if (k0 > DDIM) k0 = DDIM;
    unsigned kk = (unsigned)k0;

    // Gaussian-tail quantile estimate for top-k (heuristic only; fallback is
    // exact). z ~= Phi^-1(1 - k/(2D)) via two Mills-ratio fixed-point steps,
    // shrunk by 0.75 for margin. k=256,D=2048 -> pivot ~= 1.30*sigma,
    // E[candidates] ~= 396 >> 256.
    const float f2 = (float)kk * (0.5f / (float)DDIM);
    float z = sqrtf(fmaxf(-2.0f * __logf(f2), 0.0f));
    z = sqrtf(fmaxf(-2.0f * __logf(f2 * 2.5066283f * z), 0.0f));
    z = sqrtf(fmaxf(-2.0f * __logf(f2 * 2.5066283f * z), 0.0f));
    const float piv = 0.75f * z * sigma;
    unsigned pv = (piv > 0.0f && piv < 3.0e38f) ? __float_as_uint(piv) : 0u;

    // ---- radix select over candidates {mb >= pv} ----
    unsigned prefix = 0u, thr = 0u;
    int r = 0;
    for (;;) {
        const int      shift  = (r == 0) ? 20 : (r == 1) ? 9 : 0;
        const unsigned dmask  = (r == 2) ? 0x1FFu : 0x7FFu;
        const unsigned himask = (r == 0) ? 0u
                              : (r == 1) ? 0xFFF00000u : 0xFFFFFE00u;

        #pragma unroll
        for (int i = 0; i < 8; ++i) {
            const unsigned m = mb[i];
            if (m >= pv && (m & himask) == prefix)
                atomicAdd(&hist[(m >> shift) & dmask], 1u);
        }
        __syncthreads();                   // A: counts ready

        const uint4 h0 = h4[2*tid];
        const uint4 h1 = h4[2*tid + 1];
        unsigned c[8] = {h0.x, h0.y, h0.z, h0.w, h1.x, h1.y, h1.z, h1.w};
        unsigned sfx[8];
        sfx[7] = c[7];
        #pragma unroll
        for (int i = 6; i >= 0; --i) sfx[i] = sfx[i+1] + c[i];
        const unsigned T = sfx[0];
        unsigned suf = T;
        #pragma unroll
        for (int off = 1; off < 64; off <<= 1) {
            const unsigned t = __shfl_down(suf, off, 64);
            if (lane + off < 64) suf += t;
        }
        if (lane == 0) wtot[wid] = suf;
        __syncthreads();                   // B: wtot ready; hist reads done

        unsigned above = suf - T;
        #pragma unroll
        for (int w = 0; w < 4; ++w)
            if (w > wid) above += wtot[w];
        #pragma unroll
        for (int i = 0; i < 8; ++i) {
            const unsigned cge = above + sfx[i];
            const unsigned cgt = cge - c[i];
            if (cgt < kk && kk <= cge) {   // unique crossing bin
                const unsigned kloc = kk - cgt;
                s_prefix = prefix | ((unsigned)(8*tid + i) << shift);
                s_kk  = kloc;
                s_cnt = c[i];
                s_thr = (kloc == 1u) ? 0u : 0xFFFFFFFFu; // init for min/max exit
            }
        }
        // tid 0's first cge is the histogram total: < kk means the prefilter
        // kept too few candidates -> signal fallback (exactly one writer of
        // s_cnt per iteration either way).
        if (tid == 0 && (above + sfx[0]) < kk) s_cnt = 0u;
        if (r < 2) {                       // clear for next round
            h4[2*tid]     = zero4;
            h4[2*tid + 1] = zero4;
        }
        __syncthreads();                   // C: s_* visible + clear done

        const unsigned cnt = s_cnt;        // block-uniform
        if (cnt == 0u) { pv = 0u; continue; }   // rerun round 0 over all elems
        prefix = s_prefix;
        const unsigned kloc = s_kk;
        if (r == 2) { thr = prefix; break; }    // all 31 bits resolved
        if (kloc == 1u || kloc == cnt) {
            // target is the max (min) of elements matching the prefix
            const unsigned hm = (r == 0) ? 0xFFF00000u : 0xFFFFFE00u;
            if (kloc == 1u) {
                #pragma unroll
                for (int i = 0; i < 8; ++i)
                    if (mb[i] >= pv && (mb[i] & hm) == prefix)
                        atomicMax(&s_thr, mb[i]);
            } else {
                #pragma unroll
                for (int i = 0; i < 8; ++i)
                    if (mb[i] >= pv && (mb[i] & hm) == prefix)
                        atomicMin(&s_thr, mb[i]);
            }
            __syncthreads();               // D: s_thr ready
            thr = s_thr;
            break;
        }
        kk = kloc;
        ++r;
    }

    // ---- epilogue: out = x + (|xn| >= thr) * xn * gamma ----
    f4 o1, o2;
    o1.x = a.x + (mb[0] >= thr ? nx[0] * ga.x : 0.0f);
    o1.y = a.y + (mb[1] >= thr ? nx[1] * ga.y : 0.0f);
    o1.z = a.z + (mb[2] >= thr ? nx[2] * ga.z : 0.0f);
    o1.w = a.w + (mb[3] >= thr ? nx[3] * ga.w : 0.0f);
    o2.x = b.x + (mb[4] >= thr ? nx[4] * gb.x : 0.0f);
    o2.y = b.y + (mb[5] >= thr ? nx[5] * gb.y : 0.0f);
    o2.z = b.z + (mb[6] >= thr ? nx[6] * gb.z : 0.0f);
    o2.w = b.w + (mb[7] >= thr ? nx[7] * gb.w : 0.0f);

    f4* o4 = (f4*)(out + row * (long)DDIM);
    __builtin_nontemporal_store(o1, o4 + tid);
    __builtin_nontemporal_store(o2, o4 + tid + 256);
}

extern "C" void kernel_launch(void* const* d_in, const int* in_sizes, int n_in,
                              void* d_out, int out_size, void* d_ws, size_t ws_size,
                              hipStream_t stream) {
    const float* x      = (const float*)d_in[0];
    const float* weight = (const float*)d_in[1];
    const float* gamma  = (const float*)d_in[2];
    const int*   kp     = (const int*)d_in[3];
    const int D = in_sizes[1];          // 2048
    const int N = in_sizes[0] / D;      // 32768
    (void)n_in; (void)out_size; (void)d_ws; (void)ws_size;

    sparse_topk_rmsnorm_kernel<<<dim3(N), dim3(THREADS), 0, stream>>>(
        x, weight, gamma, kp, (float*)d_out);
}